// Round 8
// baseline (344.391 us; speedup 1.0000x reference)
//
#include <hip/hip_runtime.h>

typedef __bf16 bf16;
typedef __bf16 bf16x2 __attribute__((ext_vector_type(2)));
typedef __bf16 bf16x4 __attribute__((ext_vector_type(4)));
typedef __bf16 bf16x8 __attribute__((ext_vector_type(8)));
typedef float floatx4 __attribute__((ext_vector_type(4)));

#define DD 768
#define NH 12
#define HDIM 64
#define BB 16
#define NN 1024
#define MTOT (BB*NN)   // 16384
#define WELEM (DD*DD)  // 589824

__device__ __forceinline__ void async_cp16(const void* g, void* l) {
  __builtin_amdgcn_global_load_lds((const __attribute__((address_space(1))) void*)g,
                                   (__attribute__((address_space(3))) void*)l, 16, 0, 0);
}

// ------------- Fused LayerNorm (blocks 0..4095) + weight-convert (4096..6975) ----
// Weight conversion needs 5*WELEM/4 = 737280 quads -> 2880 blocks of 256.
__global__ __launch_bounds__(256) void prep_kernel(const float* __restrict__ x,
    const float* __restrict__ lnw, const float* __restrict__ lnb, bf16* __restrict__ A,
    const float* __restrict__ w0, const float* __restrict__ w1, const float* __restrict__ w2,
    const float* __restrict__ w3, const float* __restrict__ w4, bf16* __restrict__ Wb) {
  int blk = blockIdx.x;
  if (blk < 4096) {
    int row = blk * 4 + (threadIdx.x >> 6);
    int lane = threadIdx.x & 63;
    const float4* xr = (const float4*)(x + (size_t)row * DD);
    float4 v[3];
    float s = 0.f;
#pragma unroll
    for (int i = 0; i < 3; i++) {
      v[i] = xr[lane + 64 * i];
      s += v[i].x + v[i].y + v[i].z + v[i].w;
    }
#pragma unroll
    for (int o = 32; o; o >>= 1) s += __shfl_xor(s, o);
    float mu = s * (1.f / 768.f);
    float vs = 0.f;
#pragma unroll
    for (int i = 0; i < 3; i++) {
      float dx;
      dx = v[i].x - mu; vs += dx * dx;
      dx = v[i].y - mu; vs += dx * dx;
      dx = v[i].z - mu; vs += dx * dx;
      dx = v[i].w - mu; vs += dx * dx;
    }
#pragma unroll
    for (int o = 32; o; o >>= 1) vs += __shfl_xor(vs, o);
    float rstd = rsqrtf(vs * (1.f / 768.f) + 1e-5f);
    const float4* wv = (const float4*)lnw;
    const float4* bv = (const float4*)lnb;
    bf16* Ar = A + (size_t)row * DD;
#pragma unroll
    for (int i = 0; i < 3; i++) {
      int c4 = lane + 64 * i;
      float4 ww = wv[c4], bb = bv[c4];
      bf16x4 pk;
      pk[0] = (bf16)((v[i].x - mu) * rstd * ww.x + bb.x);
      pk[1] = (bf16)((v[i].y - mu) * rstd * ww.y + bb.y);
      pk[2] = (bf16)((v[i].z - mu) * rstd * ww.z + bb.z);
      pk[3] = (bf16)((v[i].w - mu) * rstd * ww.w + bb.w);
      *(bf16x4*)(Ar + c4 * 4) = pk;
    }
  } else {
    int i = (blk - 4096) * 256 + threadIdx.x;   // 0..737279 quads
    int which = i / (WELEM / 4);
    int off = (i % (WELEM / 4)) * 4;
    const float* s = which == 0 ? w0 : which == 1 ? w1 : which == 2 ? w2 : which == 3 ? w3 : w4;
    float4 v = *(const float4*)(s + off);
    bf16x4 pk;
    pk[0] = (bf16)v.x; pk[1] = (bf16)v.y; pk[2] = (bf16)v.z; pk[3] = (bf16)v.w;
    *(bf16x4*)(Wb + (size_t)i * 4) = pk;
  }
}

// -------- GEMM body: 128x128 tile, BK=32, dbuf, one barrier/iter -------------
// LDS swizzle: storage colgroup = mem colgroup ^ ((row>>1)&3)  (4 groups of 8)
// Staging: 8 slices of 16 rows per array; wave w owns slices {w, w+4}.
//   lane l -> row sliceBase + (l>>2), storage cg (l&3), source cg (l&3)^((l>>3)&3).
// EPI: 0 relu->bf16, 1 plain->bf16, 3 sigmoid->bf16, 4 final f32, 5 rope->bf16
// MFMA operands swapped (computes C^T): lane holds row gm = ..+l16, cols gc..gc+3.
#define STG32 4096   // elements per stage per array (128*32)
template<int EPI>
__device__ __forceinline__ void gemm_body(
    int bm, int bn, int bnl,
    const bf16* __restrict__ Aop, const bf16* __restrict__ W,
    const float* __restrict__ bias, const float* __restrict__ rope,
    bf16* __restrict__ Cb, float* __restrict__ Cf,
    const float* __restrict__ Xres, const bf16* __restrict__ Gate,
    bf16* As, bf16* Bs) {
  int tid = threadIdx.x;
  int wave = tid >> 6, lane = tid & 63;
  int quad = lane >> 4, l16 = lane & 15;
  int wm = wave & 1, wn = wave >> 1;
  int srow = lane >> 2;                       // 0..15 within a 16-row slice
  int scg = (lane & 3) ^ ((lane >> 3) & 3);   // source colgroup for this lane

  const bf16* Ag = Aop + ((size_t)(bm * 128) + srow) * DD + scg * 8;
  const bf16* Bg = W + ((size_t)(bn * 128) + srow) * DD + scg * 8;

  floatx4 acc[4][4];
#pragma unroll
  for (int i = 0; i < 4; i++)
#pragma unroll
    for (int j = 0; j < 4; j++)
      acc[i][j] = (floatx4){0.f, 0.f, 0.f, 0.f};

  int swz = (l16 >> 1) & 3;

  // prologue: stage k-tile 0 into stage 0
#pragma unroll
  for (int it = 0; it < 2; it++) {
    int c = it * 4 + wave;                    // slice 0..7 (16 rows each)
    async_cp16(Ag + (size_t)(c * 16) * DD, &As[c * 512]);
    async_cp16(Bg + (size_t)(c * 16) * DD, &Bs[c * 512]);
  }

  for (int i = 0; i < 24; i++) {
    __syncthreads();   // stage i&1 ready (vmcnt drained); stage (i+1)&1 free
    if (i < 23) {
      int k0 = (i + 1) * 32;
      int so = ((i + 1) & 1) * STG32;
#pragma unroll
      for (int it = 0; it < 2; it++) {
        int c = it * 4 + wave;
        async_cp16(Ag + (size_t)(c * 16) * DD + k0, &As[so + c * 512]);
        async_cp16(Bg + (size_t)(c * 16) * DD + k0, &Bs[so + c * 512]);
      }
    }
    int bo = (i & 1) * STG32;
    int cg = quad ^ swz;
    bf16x8 a[4], b[4];
#pragma unroll
    for (int j = 0; j < 4; j++) a[j] = *(const bf16x8*)&As[bo + (wm * 64 + j * 16 + l16) * 32 + cg * 8];
#pragma unroll
    for (int j = 0; j < 4; j++) b[j] = *(const bf16x8*)&Bs[bo + (wn * 64 + j * 16 + l16) * 32 + cg * 8];
#pragma unroll
    for (int mi = 0; mi < 4; mi++)
#pragma unroll
      for (int ni = 0; ni < 4; ni++)
        acc[mi][ni] = __builtin_amdgcn_mfma_f32_16x16x32_bf16(b[ni], a[mi], acc[mi][ni], 0, 0, 0);
  }

#pragma unroll
  for (int mi = 0; mi < 4; mi++) {
    int gm = bm * 128 + wm * 64 + mi * 16 + l16;
#pragma unroll
    for (int ni = 0; ni < 4; ni++) {
      int gc = bnl * 128 + wn * 64 + ni * 16 + quad * 4;
      float4 bz = *(const float4*)&bias[gc];
      float v0 = acc[mi][ni][0] + bz.x;
      float v1 = acc[mi][ni][1] + bz.y;
      float v2 = acc[mi][ni][2] + bz.z;
      float v3 = acc[mi][ni][3] + bz.w;
      size_t idx = (size_t)gm * DD + gc;
      if (EPI == 4) {
        bf16x4 g = *(const bf16x4*)&Gate[idx];
        float4 xr = *(const float4*)&Xres[idx];
        float4 o;
        o.x = xr.x + (float)g[0] * v0;
        o.y = xr.y + (float)g[1] * v1;
        o.z = xr.z + (float)g[2] * v2;
        o.w = xr.w + (float)g[3] * v3;
        *(float4*)&Cf[idx] = o;
      } else if (EPI == 5) {
        // fused RoPE: row gm = token, gc = h*64 + c0 (c0 multiple of 4)
        int n = gm & (NN - 1);
        int h = gc >> 6, c0 = gc & 63;
        int j0 = c0 >> 1;
        float4 ang = *(const float4*)&rope[n * HDIM + c0];
        float s0, cc0, s1, cc1, s2, cc2, s3, cc3;
        __sincosf(ang.x, &s0, &cc0);
        __sincosf(ang.y, &s1, &cc1);
        __sincosf(ang.z, &s2, &cc2);
        __sincosf(ang.w, &s3, &cc3);
        bf16x2 lo, hi;
        lo[0] = (bf16)(v0 * cc0 - v1 * s0);
        lo[1] = (bf16)(v2 * cc2 - v3 * s2);
        hi[0] = (bf16)(v0 * s1 + v1 * cc1);
        hi[1] = (bf16)(v2 * s3 + v3 * cc3);
        bf16* base = Cb + (size_t)gm * DD + h * HDIM;
        *(bf16x2*)&base[j0] = lo;
        *(bf16x2*)&base[32 + j0] = hi;
      } else {
        bf16x4 pk;
        if (EPI == 0) {
          pk[0] = (bf16)fmaxf(v0, 0.f); pk[1] = (bf16)fmaxf(v1, 0.f);
          pk[2] = (bf16)fmaxf(v2, 0.f); pk[3] = (bf16)fmaxf(v3, 0.f);
        } else if (EPI == 1) {
          pk[0] = (bf16)v0; pk[1] = (bf16)v1; pk[2] = (bf16)v2; pk[3] = (bf16)v3;
        } else {
          pk[0] = (bf16)(1.f / (1.f + __expf(-v0)));
          pk[1] = (bf16)(1.f / (1.f + __expf(-v1)));
          pk[2] = (bf16)(1.f / (1.f + __expf(-v2)));
          pk[3] = (bf16)(1.f / (1.f + __expf(-v3)));
        }
        *(bf16x4*)&Cb[idx] = pk;
      }
    }
  }
}

// bm count = 128; xcd owns 16 bm. Grid = 128 * NBN.
template<int EPI_LO, int EPI_HI, int NBN>
__global__ __launch_bounds__(256, 4) void gemm_kernel(
    const bf16* __restrict__ Aop, const bf16* __restrict__ W,
    const float* __restrict__ bias_lo, const float* __restrict__ bias_hi,
    const float* __restrict__ rope,
    bf16* __restrict__ C_lo, bf16* __restrict__ C_hi, float* __restrict__ Cf,
    const float* __restrict__ Xres, const bf16* __restrict__ Gate) {
  __shared__ bf16 As[2 * STG32];
  __shared__ bf16 Bs[2 * STG32];
  int blk = blockIdx.x;
  int xcd = blk & 7, slot = blk >> 3;
  int bm = xcd * 16 + slot / NBN;
  int bn = slot % NBN;
  if (NBN == 12 && bn >= 6) {
    gemm_body<EPI_HI>(bm, bn, bn - 6, Aop, W, bias_hi, rope, C_hi, Cf, Xres, Gate, As, Bs);
  } else {
    gemm_body<EPI_LO>(bm, bn, bn, Aop, W, bias_lo, rope, C_lo, Cf, Xres, Gate, As, Bs);
  }
}

// ---- Attention: T = QKr^T @ V (64x64) via LDS-transposed chunks; attn = QKr @ T/8
// 768 blocks = (xcd, bh-local, quarter). Wave w owns T rows 16w..16w+15 (no x-wave
// reduction). Stage-2 computes 256 rows (quarter q).
#define TQS 136   // LDS row stride for transposed Q/V (136*2B = 272 B)
__global__ __launch_bounds__(256, 2) void attn_kernel(const bf16* __restrict__ QKr,
    const bf16* __restrict__ V, bf16* __restrict__ attn) {
  __shared__ bf16 Qt[64 * TQS];
  __shared__ bf16 Vt[64 * TQS];
  __shared__ bf16 Tbf[64 * 72];
  int blk = blockIdx.x;
  int xcd = blk & 7, s = blk >> 3;
  int bhl = s >> 2, q = s & 3;
  int bh = xcd * 24 + bhl;
  int b_ = bh / NH, h_ = bh % NH;
  int tid = threadIdx.x, wave = tid >> 6, lane = tid & 63;
  int quad = lane >> 4, l16 = lane & 15;

  const bf16* Qbase = QKr + (size_t)(b_ * NN) * DD + h_ * HDIM;
  const bf16* Vbase = V + (size_t)(b_ * NN) * DD + h_ * HDIM;

  floatx4 acc1[4];
#pragma unroll
  for (int i = 0; i < 4; i++) acc1[i] = (floatx4){0.f, 0.f, 0.f, 0.f};

  // staging decomposition: p = n-pair (0..63), dq = d-quarter (0..3)
  int p = tid & 63, dq = tid >> 6;

  for (int c = 0; c < 8; c++) {
    int n0 = c * 128 + p * 2;
    bf16x8 q0a = *(const bf16x8*)&Qbase[(size_t)n0 * DD + dq * 16];
    bf16x8 q0b = *(const bf16x8*)&Qbase[(size_t)n0 * DD + dq * 16 + 8];
    bf16x8 q1a = *(const bf16x8*)&Qbase[(size_t)(n0 + 1) * DD + dq * 16];
    bf16x8 q1b = *(const bf16x8*)&Qbase[(size_t)(n0 + 1) * DD + dq * 16 + 8];
    bf16x8 v0a = *(const bf16x8*)&Vbase[(size_t)n0 * DD + dq * 16];
    bf16x8 v0b = *(const bf16x8*)&Vbase[(size_t)n0 * DD + dq * 16 + 8];
    bf16x8 v1a = *(const bf16x8*)&Vbase[(size_t)(n0 + 1) * DD + dq * 16];
    bf16x8 v1b = *(const bf16x8*)&Vbase[(size_t)(n0 + 1) * DD + dq * 16 + 8];
    __syncthreads();   // previous chunk's MFMA LDS reads done
    int nl = p * 2;
#pragma unroll
    for (int j = 0; j < 8; j++) {
      bf16x2 qa; qa[0] = q0a[j]; qa[1] = q1a[j];
      bf16x2 qb; qb[0] = q0b[j]; qb[1] = q1b[j];
      bf16x2 va; va[0] = v0a[j]; va[1] = v1a[j];
      bf16x2 vb; vb[0] = v0b[j]; vb[1] = v1b[j];
      *(bf16x2*)&Qt[(dq * 16 + j) * TQS + nl] = qa;
      *(bf16x2*)&Qt[(dq * 16 + 8 + j) * TQS + nl] = qb;
      *(bf16x2*)&Vt[(dq * 16 + j) * TQS + nl] = va;
      *(bf16x2*)&Vt[(dq * 16 + 8 + j) * TQS + nl] = vb;
    }
    __syncthreads();   // transposed chunk visible
#pragma unroll
    for (int ks = 0; ks < 4; ks++) {
      bf16x8 a = *(const bf16x8*)&Qt[(wave * 16 + l16) * TQS + ks * 32 + quad * 8];
#pragma unroll
      for (int ni = 0; ni < 4; ni++) {
        bf16x8 b = *(const bf16x8*)&Vt[(ni * 16 + l16) * TQS + ks * 32 + quad * 8];
        acc1[ni] = __builtin_amdgcn_mfma_f32_16x16x32_bf16(a, b, acc1[ni], 0, 0, 0);
      }
    }
  }
  __syncthreads();
  // Tbf[d2][d1] = T[d1][d2]/8 ; d1 = 16w+quad*4+r, d2 = ni*16+l16
#pragma unroll
  for (int ni = 0; ni < 4; ni++)
#pragma unroll
    for (int r = 0; r < 4; r++)
      Tbf[(ni * 16 + l16) * 72 + wave * 16 + quad * 4 + r] = (bf16)(acc1[ni][r] * 0.125f);
  __syncthreads();

  // stage 2: attn[n][d2] = sum_d1 QKr[n][d1] * Tbf[d2][d1]
  bf16* Ao = attn + (size_t)(b_ * NN) * DD + h_ * HDIM;
  bf16x8 Bf[4][2];
#pragma unroll
  for (int ni = 0; ni < 4; ni++)
#pragma unroll
    for (int ks = 0; ks < 2; ks++)
      Bf[ni][ks] = *(const bf16x8*)&Tbf[(ni * 16 + l16) * 72 + ks * 32 + quad * 8];

#pragma unroll
  for (int mi = 0; mi < 4; mi++) {
    int nrow = q * 256 + wave * 64 + mi * 16;
    bf16x8 a0 = *(const bf16x8*)&Qbase[(size_t)(nrow + l16) * DD + quad * 8];
    bf16x8 a1 = *(const bf16x8*)&Qbase[(size_t)(nrow + l16) * DD + 32 + quad * 8];
    floatx4 o[4];
#pragma unroll
    for (int ni = 0; ni < 4; ni++) o[ni] = (floatx4){0.f, 0.f, 0.f, 0.f};
#pragma unroll
    for (int ni = 0; ni < 4; ni++) {
      o[ni] = __builtin_amdgcn_mfma_f32_16x16x32_bf16(a0, Bf[ni][0], o[ni], 0, 0, 0);
      o[ni] = __builtin_amdgcn_mfma_f32_16x16x32_bf16(a1, Bf[ni][1], o[ni], 0, 0, 0);
    }
#pragma unroll
    for (int ni = 0; ni < 4; ni++)
#pragma unroll
      for (int r = 0; r < 4; r++)
        Ao[(size_t)(nrow + quad * 4 + r) * DD + ni * 16 + l16] = (bf16)o[ni][r];
  }
}

extern "C" void kernel_launch(void* const* d_in, const int* in_sizes, int n_in,
                              void* d_out, int out_size, void* d_ws, size_t ws_size,
                              hipStream_t stream) {
  const float* x      = (const float*)d_in[0];
  const float* rope   = (const float*)d_in[1];
  const float* ln_w   = (const float*)d_in[2];
  const float* ln_b   = (const float*)d_in[3];
  const float* enc_w  = (const float*)d_in[4];
  const float* enc_b  = (const float*)d_in[5];
  const float* qk_w   = (const float*)d_in[6];
  const float* qk_b   = (const float*)d_in[7];
  const float* v_w    = (const float*)d_in[8];
  const float* v_b    = (const float*)d_in[9];
  const float* out_w  = (const float*)d_in[10];
  const float* out_b  = (const float*)d_in[11];
  const float* gate_w = (const float*)d_in[12];
  const float* gate_b = (const float*)d_in[13];

  char* w = (char*)d_ws;
  const size_t S = (size_t)MTOT * DD * 2;
  bf16* A     = (bf16*)(w);
  bf16* L     = (bf16*)(w + S);        // reused as attnb
  bf16* Gate  = (bf16*)(w + 2 * S);
  bf16* QKr   = (bf16*)(w + 3 * S);
  bf16* Vb    = (bf16*)(w + 4 * S);
  bf16* Wb    = (bf16*)(w + 6 * S);    // weights bf16: enc, gate, qk, v, out
  bf16* attnb = L;

  // LN (4096 blocks) + weight conversion (2880 blocks = 737280 quads)
  prep_kernel<<<dim3(4096 + 2880), dim3(256), 0, stream>>>(
      x, ln_w, ln_b, A, enc_w, gate_w, qk_w, v_w, out_w, Wb);

  // GEMM1: [L | Gate] = [relu | sigmoid](A @ [enc; gate]^T + b)
  gemm_kernel<0, 3, 12><<<dim3(1536), dim3(256), 0, stream>>>(
      A, Wb, enc_b, gate_b, nullptr, L, Gate, nullptr, nullptr, nullptr);
  // GEMM2: [QKr (rope fused) | V] = L @ [qk; v]^T + b
  gemm_kernel<5, 1, 12><<<dim3(1536), dim3(256), 0, stream>>>(
      L, Wb + 2 * (size_t)WELEM, qk_b, v_b, rope, QKr, Vb, nullptr, nullptr, nullptr);
  // attn = QKr @ (QKr^T @ V) / 8
  attn_kernel<<<dim3(768), dim3(256), 0, stream>>>(QKr, Vb, attnb);
  // GEMM3: out = x + Gate * (attnb @ out_w^T + b)
  gemm_kernel<4, 4, 6><<<dim3(768), dim3(256), 0, stream>>>(
      attnb, Wb + 4 * (size_t)WELEM, out_b, nullptr, nullptr, nullptr, nullptr,
      (float*)d_out, x, Gate);
}